// Round 16
// baseline (129.648 us; speedup 1.0000x reference)
//
#include <hip/hip_runtime.h>
#include <hip/hip_bf16.h>
#include <cstdint>

typedef __attribute__((ext_vector_type(4))) float f32x4;
typedef __attribute__((ext_vector_type(8))) short bf16x8;

__device__ __forceinline__ ushort f2bf(float f) {
  unsigned u = __builtin_bit_cast(unsigned, f);
  u += 0x7fffu + ((u >> 16) & 1u);
  return (ushort)(u >> 16);
}

__device__ __forceinline__ void gload_lds16(const ushort* g, ushort* l) {
  __builtin_amdgcn_global_load_lds(
      (const __attribute__((address_space(1))) unsigned int*)g,
      (__attribute__((address_space(3))) unsigned int*)l, 16, 0, 0);
}

__device__ __forceinline__ void hard_barrier() {
  __builtin_amdgcn_sched_barrier(0);
  __builtin_amdgcn_s_barrier();
  __builtin_amdgcn_sched_barrier(0);
}

template <int N>
__device__ __forceinline__ void wait_vm() {
  if constexpr (N == 0) asm volatile("s_waitcnt vmcnt(0)" ::: "memory");
  else if constexpr (N == 2) asm volatile("s_waitcnt vmcnt(2)" ::: "memory");
  else if constexpr (N == 3) asm volatile("s_waitcnt vmcnt(3)" ::: "memory");
  else if constexpr (N == 4) asm volatile("s_waitcnt vmcnt(4)" ::: "memory");
  else if constexpr (N == 6) asm volatile("s_waitcnt vmcnt(6)" ::: "memory");
  else static_assert(N < 0, "unsupported vmcnt");
}

__device__ __forceinline__ float elu1(float v) {
  return (v > 0.f) ? (v + 1.f) : __expf(v);
}

// ---------- kernel 0: fused prep (R10 verbatim) ----------
__global__ __launch_bounds__(256) void prep_kernel(const float4* __restrict__ x,
                                                   ushort4* __restrict__ xb,
                                                   const float* __restrict__ W,
                                                   ushort* __restrict__ Wt) {
  if (blockIdx.x < 2048) {
    const int n4 = 16384 * 1024 / 4;
    const int stride = 2048 * 256;
    for (int i = blockIdx.x * 256 + threadIdx.x; i < n4; i += stride) {
      float4 f = x[i];
      ushort4 o;
      o.x = f2bf(f.x); o.y = f2bf(f.y); o.z = f2bf(f.z); o.w = f2bf(f.w);
      xb[i] = o;
    }
  } else {
    __shared__ float tile[32][33];
    const int tb = blockIdx.x - 2048;     // 0..1535
    const int n0 = (tb % 48) * 32;
    const int k0 = (tb / 48) * 32;
    const int tx = threadIdx.x & 31;
    const int ty = threadIdx.x >> 5;      // 0..7
    #pragma unroll
    for (int p = 0; p < 4; ++p) {
      int k = k0 + ty + p * 8;
      tile[ty + p * 8][tx] = W[(size_t)k * 1536 + n0 + tx];
    }
    __syncthreads();
    #pragma unroll
    for (int p = 0; p < 4; ++p) {
      int n = n0 + ty + p * 8;
      Wt[(size_t)n * 1024 + k0 + tx] = f2bf(tile[tx][ty + p * 8]);
    }
  }
}

// ============================================================================
// R15 core (proven: 0 conflicts, 2 blocks/CU): 128x256 tile, 512 thr = 8
// waves (2M x 4N), wave tile 64x64, BK=32, 3 slots x 24KB = 72 KiB.
// Pipeline: stage(t+2); compute(t); vmcnt(3); one barrier per tile.
// ============================================================================
template <int LDA, int LDB, int NT>
__device__ __forceinline__ void gemm_core32(const ushort* __restrict__ A,
                                            const ushort* __restrict__ Bt,
                                            int row0, int col0, f32x4 acc[4][4],
                                            ushort* lds) {
  const int tid = threadIdx.x;
  const int l = tid & 63;
  const int wid = tid >> 6;
  const int fr = l & 15;
  const int fq = l >> 4;
  const int wr = wid >> 2;
  const int wc = wid & 3;

  const int sc = ((tid & 3) ^ ((tid >> 3) & 3)) * 8;  // pre-swizzled source col
  const ushort* aS = A + (size_t)(row0 + (tid >> 2)) * LDA + sc;
  const ushort* bS = Bt + (size_t)(col0 + (tid >> 2)) * LDB + sc;

  auto stage = [&](int t) {
    ushort* base = lds + (t % 3) * 12288 + tid * 8;
    gload_lds16(aS + t * 32, base);
    gload_lds16(bS + t * 32, base + 4096);
    gload_lds16(bS + (size_t)128 * LDB + t * 32, base + 8192);
  };

  const int sig = fq ^ ((fr >> 1) & 3);
  const int aOff = wr * 2048 + fr * 32 + sig * 8;
  const int bOff = 4096 + wc * 2048 + fr * 32 + sig * 8;

  auto compute = [&](int t) {
    const ushort* sb = lds + (t % 3) * 12288;
    bf16x8 av[4], bv[4];
    #pragma unroll
    for (int m = 0; m < 4; ++m) av[m] = *(const bf16x8*)(sb + aOff + m * 512);
    #pragma unroll
    for (int n = 0; n < 4; ++n) bv[n] = *(const bf16x8*)(sb + bOff + n * 512);
    __builtin_amdgcn_s_setprio(1);
    #pragma unroll
    for (int m = 0; m < 4; ++m)
      #pragma unroll
      for (int n = 0; n < 4; ++n)
        acc[m][n] = __builtin_amdgcn_mfma_f32_16x16x32_bf16(av[m], bv[n], acc[m][n], 0, 0, 0);
    __builtin_amdgcn_s_setprio(0);
  };

  stage(0);
  stage(1);
  wait_vm<3>();
  hard_barrier();

  #pragma unroll 3
  for (int t = 0; t < NT; ++t) {
    if (t + 2 < NT) stage(t + 2);
    compute(t);
    if (t + 2 < NT) {
      wait_vm<3>();
      hard_barrier();
    } else if (t + 1 < NT) {
      wait_vm<0>();
      hard_barrier();
    }
  }
}

// ============================================================================
// NEW: high-reuse co-resident core. 256x128 block tile, 256 thr = 4 waves
// (2M x 2N), wave tile 128x64 (MREP=8, NREP=4): 12 ds_read_b128 per 32 MFMA
// = 43.7 FLOP/LDS-byte (+37% vs 64x64's 32) — attacks the CU-shared LDS read
// BW that R15's counters identified as the wall. BK=32, 3 slots x 24KB
// (A 256x32 = 16KB | B 128x32 = 8KB) = 72 KiB -> 2 blocks/CU (8 waves/CU).
// Pipeline/swizzle identical to R15 core (vmcnt(6): 6 gloads/thread/tile).
// Staging: A slots s = p*256+tid (p=0..3): row = p*64+(tid>>2), phys (tid&3);
// row stride 64 is mult of 4 -> lam = (tid&3)^((tid>>3)&3) same for all p.
// B: p=0..1 same formula. Read sig = fq^((fr>>1)&3) (R15-verified pattern).
// ============================================================================
template <int LDA, int LDB, int NT>
__device__ __forceinline__ void gemm_core_hr(const ushort* __restrict__ A,
                                             const ushort* __restrict__ Bt,
                                             int row0, int col0, f32x4 acc[8][4],
                                             ushort* lds) {
  const int tid = threadIdx.x;  // 0..255
  const int l = tid & 63;
  const int wid = tid >> 6;  // 0..3
  const int fr = l & 15;
  const int fq = l >> 4;
  const int wr = wid >> 1;
  const int wc = wid & 1;

  const int sc = ((tid & 3) ^ ((tid >> 3) & 3)) * 8;  // pre-swizzled source col
  const ushort* aS = A + (size_t)(row0 + (tid >> 2)) * LDA + sc;
  const ushort* bS = Bt + (size_t)(col0 + (tid >> 2)) * LDB + sc;

  auto stage = [&](int t) {
    ushort* base = lds + (t % 3) * 12288 + tid * 8;
    #pragma unroll
    for (int p = 0; p < 4; ++p)
      gload_lds16(aS + (size_t)(p * 64) * LDA + t * 32, base + p * 2048);
    #pragma unroll
    for (int p = 0; p < 2; ++p)
      gload_lds16(bS + (size_t)(p * 64) * LDB + t * 32, base + 8192 + p * 2048);
  };

  const int sig = fq ^ ((fr >> 1) & 3);
  const int aOff = wr * 4096 + fr * 32 + sig * 8;          // + m*512, m=0..7
  const int bOff = 8192 + wc * 2048 + fr * 32 + sig * 8;   // + n*512, n=0..3

  auto compute = [&](int t) {
    const ushort* sb = lds + (t % 3) * 12288;
    bf16x8 bv[4];
    #pragma unroll
    for (int n = 0; n < 4; ++n) bv[n] = *(const bf16x8*)(sb + bOff + n * 512);
    #pragma unroll
    for (int mh = 0; mh < 2; ++mh) {
      bf16x8 av[4];
      #pragma unroll
      for (int mm = 0; mm < 4; ++mm)
        av[mm] = *(const bf16x8*)(sb + aOff + (mh * 4 + mm) * 512);
      __builtin_amdgcn_s_setprio(1);
      #pragma unroll
      for (int mm = 0; mm < 4; ++mm)
        #pragma unroll
        for (int n = 0; n < 4; ++n)
          acc[mh * 4 + mm][n] =
              __builtin_amdgcn_mfma_f32_16x16x32_bf16(av[mm], bv[n], acc[mh * 4 + mm][n], 0, 0, 0);
      __builtin_amdgcn_s_setprio(0);
    }
  };

  stage(0);
  stage(1);
  wait_vm<6>();
  hard_barrier();

  #pragma unroll 3
  for (int t = 0; t < NT; ++t) {
    if (t + 2 < NT) stage(t + 2);
    compute(t);
    if (t + 2 < NT) {
      wait_vm<6>();
      hard_barrier();
    } else if (t + 1 < NT) {
      wait_vm<0>();
      hard_barrier();
    }
  }
}

// ---------- kernel 1: qkv GEMM (high-reuse core); emits q, kT, vT ----------
__global__ __launch_bounds__(256, 2) void gemm_qkv_kernel(const ushort* __restrict__ xb,
                                                          const ushort* __restrict__ wt,
                                                          ushort* __restrict__ q,
                                                          ushort* __restrict__ kT,
                                                          ushort* __restrict__ vT) {
  __shared__ ushort lds[36864];  // 72 KiB -> 2 blocks/CU
  f32x4 acc[8][4] = {};
  const int row0 = blockIdx.x * 256;
  const int col0 = blockIdx.y * 128;
  gemm_core_hr<1024, 1024, 32>(xb, wt, row0, col0, acc, lds);
  const int l = threadIdx.x & 63;
  const int wid = threadIdx.x >> 6;
  const int wr = wid >> 1, wc = wid & 1;
  const int fr = l & 15, fq = l >> 4;
  #pragma unroll
  for (int m = 0; m < 8; ++m) {
    #pragma unroll
    for (int n = 0; n < 4; ++n) {
      const int c = col0 + wc * 64 + n * 16 + fr;
      const int r0 = row0 + wr * 128 + m * 16 + fq * 4;  // j=0..3 consecutive rows
      if (c < 512) {
        #pragma unroll
        for (int j = 0; j < 4; ++j)
          q[(size_t)(r0 + j) * 512 + c] = f2bf(elu1(acc[m][n][j]));
      } else if (c < 1024) {
        const int d = c - 512;
        const int bh = (r0 >> 12) * 8 + (d >> 6);
        const int nn = r0 & 4095;
        ushort4 o;
        o.x = f2bf(elu1(acc[m][n][0]));
        o.y = f2bf(elu1(acc[m][n][1]));
        o.z = f2bf(elu1(acc[m][n][2]));
        o.w = f2bf(elu1(acc[m][n][3]));
        *(ushort4*)&kT[((size_t)bh * 64 + (d & 63)) * 4096 + nn] = o;
      } else {
        const int d = c - 1024;
        const int bh = (r0 >> 12) * 8 + (d >> 6);
        const int nn = r0 & 4095;
        ushort4 o;
        o.x = f2bf(acc[m][n][0]);
        o.y = f2bf(acc[m][n][1]);
        o.z = f2bf(acc[m][n][2]);
        o.w = f2bf(acc[m][n][3]);
        *(ushort4*)&vT[((size_t)bh * 64 + (d & 63)) * 4096 + nn] = o;
      }
    }
  }
}

// ---------- kernel 2: ctx partials via MFMA (R10 verbatim) ----------
__global__ __launch_bounds__(256) void ctx_mfma_kernel(const ushort* __restrict__ kT,
                                                       const ushort* __restrict__ vT,
                                                       float* __restrict__ part) {
  __shared__ ushort lds[16384];  // 32 KiB
  const int bh = blockIdx.x;
  const int sp = blockIdx.y;
  const int tid = threadIdx.x;
  const int l = tid & 63, wid = tid >> 6;
  const int fr = l & 15, fq = l >> 4;
  const int wr = wid >> 1, wc = wid & 1;

  const size_t base = (size_t)bh * 64 * 4096 + sp * 512;
  const int srow = tid >> 2;                     // 0..63
  const int lam = (tid & 3) ^ ((tid >> 3) & 3);  // logical 16B slot for phys (tid&3)
  const ushort* aG = kT + base + (size_t)srow * 4096 + lam * 8;
  const ushort* bG = vT + base + (size_t)srow * 4096 + lam * 8;

  auto stage = [&](int t) {
    ushort* d = lds + (t & 3) * 4096 + tid * 8;
    gload_lds16(aG + t * 32, d);
    gload_lds16(bG + t * 32, d + 2048);
  };

  const int sig = fq ^ ((fr >> 1) & 3);
  f32x4 acc[2][2] = {};

  auto compute = [&](int t) {
    const ushort* sb = lds + (t & 3) * 4096;
    bf16x8 av[2], bv[2];
    #pragma unroll
    for (int mm = 0; mm < 2; ++mm)
      av[mm] = *(const bf16x8*)&sb[(wr * 32 + mm * 16 + fr) * 32 + sig * 8];
    #pragma unroll
    for (int nn = 0; nn < 2; ++nn)
      bv[nn] = *(const bf16x8*)&sb[2048 + (wc * 32 + nn * 16 + fr) * 32 + sig * 8];
    #pragma unroll
    for (int mm = 0; mm < 2; ++mm)
      #pragma unroll
      for (int nn = 0; nn < 2; ++nn)
        acc[mm][nn] = __builtin_amdgcn_mfma_f32_16x16x32_bf16(av[mm], bv[nn], acc[mm][nn], 0, 0, 0);
  };

  constexpr int NT = 16;
  stage(0); stage(1); stage(2);
  for (int t = 0; t < NT; ++t) {
    if (t <= NT - 3) wait_vm<4>();
    else if (t == NT - 2) wait_vm<2>();
    else wait_vm<0>();
    hard_barrier();
    compute(t);
    hard_barrier();
    if (t + 3 < NT) stage(t + 3);
  }

  float* dst = part + ((size_t)sp * 32 + bh) * 4096;
  #pragma unroll
  for (int mm = 0; mm < 2; ++mm)
    #pragma unroll
    for (int nn = 0; nn < 2; ++nn)
      #pragma unroll
      for (int j = 0; j < 4; ++j)
        dst[(wr * 32 + mm * 16 + fq * 4 + j) * 64 + wc * 32 + nn * 16 + fr] = acc[mm][nn][j];
}

// ---------- kernel 3: W_eff^T (folds the 8-way split reduction) ----------
__global__ __launch_bounds__(256) void weff_kernel(const float* __restrict__ part,
                                                   const float* __restrict__ Wout,
                                                   ushort* __restrict__ weff) {
  const int bh = blockIdx.x;  // b*8+h
  const int h = bh & 7;
  const int m0 = blockIdx.y * 128;
  const int t = threadIdx.x;
  __shared__ float cs[64 * 64];
  __shared__ float ws[64][128];
  #pragma unroll
  for (int p = 0; p < 4; ++p) {
    const int idx = p * 1024 + t * 4;
    f32x4 s = {};
    #pragma unroll
    for (int sp = 0; sp < 8; ++sp)
      s += *(const f32x4*)&part[(size_t)sp * 131072 + (size_t)bh * 4096 + idx];
    *(f32x4*)&cs[idx] = s;
  }
  #pragma unroll
  for (int p = 0; p < 8; ++p) {
    const int e = (t >> 5) + p * 8;
    const int c = (t & 31) * 4;
    *(float4*)&ws[e][c] = *(const float4*)&Wout[(size_t)(h * 64 + e) * 1024 + m0 + c];
  }
  __syncthreads();
  const int m = t & 127;
  const int dh = (t >> 7) * 32;
  float acc[32] = {};
  for (int e = 0; e < 64; ++e) {
    const float w = ws[e][m];
    #pragma unroll
    for (int i = 0; i < 32; ++i)
      acc[i] += cs[(dh + i) * 64 + e] * w;
  }
  ushort* dst = weff + ((size_t)(bh >> 3) * 1024 + m0 + m) * 512 + h * 64 + dh;
  #pragma unroll
  for (int i = 0; i < 32; ++i) dst[i] = f2bf(acc[i]);
}

// ---------- kernel 4: out = q @ W_eff^T + b_out (fp32 out, R15 core) ----------
__global__ __launch_bounds__(512, 4) void gemm_out_kernel(const ushort* __restrict__ q,
                                                          const ushort* __restrict__ weff,
                                                          const float* __restrict__ bout,
                                                          float* __restrict__ out) {
  __shared__ ushort lds[36864];  // 72 KiB -> 2 blocks/CU, grid 512 = 1 round
  f32x4 acc[4][4] = {};
  const int row0 = blockIdx.x * 128;
  const int col0 = blockIdx.y * 256;
  const int b = row0 >> 12;  // row0 / 4096
  gemm_core32<512, 512, 16>(q, weff + (size_t)b * 1024 * 512, row0, col0, acc, lds);
  const int l = threadIdx.x & 63;
  const int wid = threadIdx.x >> 6;
  const int wr = wid >> 2, wc = wid & 3;
  const int fr = l & 15, fq = l >> 4;
  #pragma unroll
  for (int m = 0; m < 4; ++m) {
    #pragma unroll
    for (int n = 0; n < 4; ++n) {
      const int c = col0 + wc * 64 + n * 16 + fr;
      const float bb = bout[c];
      #pragma unroll
      for (int j = 0; j < 4; ++j) {
        const int r = row0 + wr * 64 + m * 16 + fq * 4 + j;
        out[(size_t)r * 1024 + c] = acc[m][n][j] + bb;
      }
    }
  }
}

extern "C" void kernel_launch(void* const* d_in, const int* in_sizes, int n_in,
                              void* d_out, int out_size, void* d_ws, size_t ws_size,
                              hipStream_t stream) {
  const float* x    = (const float*)d_in[0];
  const float* Wqkv = (const float*)d_in[1];
  const float* Wout = (const float*)d_in[2];
  const float* bout = (const float*)d_in[3];
  float* out = (float*)d_out;
  char* ws = (char*)d_ws;

  // workspace layout (bytes). part aliases xb (xb dead after gemm_qkv).
  ushort* xb   = (ushort*)(ws);              // 16384*1024*2  = 33554432
  float*  part = (float* )(ws);              // 8*32*4096*4   = 4194304 (alias)
  ushort* wt   = (ushort*)(ws + 33554432);   // 1536*1024*2   = 3145728
  ushort* q    = (ushort*)(ws + 36700160);   // 16384*512*2   = 16777216
  ushort* kT   = (ushort*)(ws + 53477376);   // 32*64*4096*2  = 16777216
  ushort* vT   = (ushort*)(ws + 70254592);   // 32*64*4096*2  = 16777216
  ushort* weff = (ushort*)(ws + 87556096);   // 4*1024*512*2  = 4194304

  prep_kernel<<<3584, 256, 0, stream>>>((const float4*)x, (ushort4*)xb, Wqkv, wt);
  gemm_qkv_kernel<<<dim3(64, 12), 256, 0, stream>>>(xb, wt, q, kT, vT);
  ctx_mfma_kernel<<<dim3(32, 8), 256, 0, stream>>>(kT, vT, part);
  weff_kernel<<<dim3(32, 8), 256, 0, stream>>>(part, Wout, weff);
  gemm_out_kernel<<<dim3(128, 4), 512, 0, stream>>>(q, weff, bout, out);
}

// Round 18
// 127.337 us; speedup vs baseline: 1.0181x; 1.0181x over previous
//
#include <hip/hip_runtime.h>
#include <hip/hip_bf16.h>
#include <cstdint>

typedef __attribute__((ext_vector_type(4))) float f32x4;
typedef __attribute__((ext_vector_type(8))) short bf16x8;

__device__ __forceinline__ ushort f2bf(float f) {
  unsigned u = __builtin_bit_cast(unsigned, f);
  u += 0x7fffu + ((u >> 16) & 1u);
  return (ushort)(u >> 16);
}

__device__ __forceinline__ void gload_lds16(const ushort* g, ushort* l) {
  __builtin_amdgcn_global_load_lds(
      (const __attribute__((address_space(1))) unsigned int*)g,
      (__attribute__((address_space(3))) unsigned int*)l, 16, 0, 0);
}

__device__ __forceinline__ void hard_barrier() {
  __builtin_amdgcn_sched_barrier(0);
  __builtin_amdgcn_s_barrier();
  __builtin_amdgcn_sched_barrier(0);
}

template <int N>
__device__ __forceinline__ void wait_vm() {
  if constexpr (N == 0) asm volatile("s_waitcnt vmcnt(0)" ::: "memory");
  else if constexpr (N == 2) asm volatile("s_waitcnt vmcnt(2)" ::: "memory");
  else if constexpr (N == 3) asm volatile("s_waitcnt vmcnt(3)" ::: "memory");
  else if constexpr (N == 4) asm volatile("s_waitcnt vmcnt(4)" ::: "memory");
  else static_assert(N < 0, "unsupported vmcnt");
}

__device__ __forceinline__ float elu1(float v) {
  return (v > 0.f) ? (v + 1.f) : __expf(v);
}

// ---------- kernel 0: fused prep (R10 verbatim) ----------
__global__ __launch_bounds__(256) void prep_kernel(const float4* __restrict__ x,
                                                   ushort4* __restrict__ xb,
                                                   const float* __restrict__ W,
                                                   ushort* __restrict__ Wt) {
  if (blockIdx.x < 2048) {
    const int n4 = 16384 * 1024 / 4;
    const int stride = 2048 * 256;
    for (int i = blockIdx.x * 256 + threadIdx.x; i < n4; i += stride) {
      float4 f = x[i];
      ushort4 o;
      o.x = f2bf(f.x); o.y = f2bf(f.y); o.z = f2bf(f.z); o.w = f2bf(f.w);
      xb[i] = o;
    }
  } else {
    __shared__ float tile[32][33];
    const int tb = blockIdx.x - 2048;     // 0..1535
    const int n0 = (tb % 48) * 32;
    const int k0 = (tb / 48) * 32;
    const int tx = threadIdx.x & 31;
    const int ty = threadIdx.x >> 5;      // 0..7
    #pragma unroll
    for (int p = 0; p < 4; ++p) {
      int k = k0 + ty + p * 8;
      tile[ty + p * 8][tx] = W[(size_t)k * 1536 + n0 + tx];
    }
    __syncthreads();
    #pragma unroll
    for (int p = 0; p < 4; ++p) {
      int n = n0 + ty + p * 8;
      Wt[(size_t)n * 1024 + k0 + tx] = f2bf(tile[tx][ty + p * 8]);
    }
  }
}

// ============================================================================
// R15 core (measured best: 850 TF, 0 bank conflicts, 2 blocks/CU): 128x256
// tile, 512 thr = 8 waves (2M x 4N), wave tile 64x64, BK=32, 3 slots x 24KB
// = 72 KiB. Pipeline: stage(t+2); compute(t); vmcnt(3); one barrier per tile.
// Swizzle: sig = fq ^ ((fr>>1)&3) (verified conflict-free), staged via
// pre-swizzled global source (rule #21).
// ============================================================================
template <int LDA, int LDB, int NT>
__device__ __forceinline__ void gemm_core32(const ushort* __restrict__ A,
                                            const ushort* __restrict__ Bt,
                                            int row0, int col0, f32x4 acc[4][4],
                                            ushort* lds) {
  const int tid = threadIdx.x;
  const int l = tid & 63;
  const int wid = tid >> 6;
  const int fr = l & 15;
  const int fq = l >> 4;
  const int wr = wid >> 2;
  const int wc = wid & 3;

  const int sc = ((tid & 3) ^ ((tid >> 3) & 3)) * 8;  // pre-swizzled source col
  const ushort* aS = A + (size_t)(row0 + (tid >> 2)) * LDA + sc;
  const ushort* bS = Bt + (size_t)(col0 + (tid >> 2)) * LDB + sc;

  auto stage = [&](int t) {
    ushort* base = lds + (t % 3) * 12288 + tid * 8;
    gload_lds16(aS + t * 32, base);
    gload_lds16(bS + t * 32, base + 4096);
    gload_lds16(bS + (size_t)128 * LDB + t * 32, base + 8192);
  };

  const int sig = fq ^ ((fr >> 1) & 3);
  const int aOff = wr * 2048 + fr * 32 + sig * 8;
  const int bOff = 4096 + wc * 2048 + fr * 32 + sig * 8;

  auto compute = [&](int t) {
    const ushort* sb = lds + (t % 3) * 12288;
    bf16x8 av[4], bv[4];
    #pragma unroll
    for (int m = 0; m < 4; ++m) av[m] = *(const bf16x8*)(sb + aOff + m * 512);
    #pragma unroll
    for (int n = 0; n < 4; ++n) bv[n] = *(const bf16x8*)(sb + bOff + n * 512);
    __builtin_amdgcn_s_setprio(1);
    #pragma unroll
    for (int m = 0; m < 4; ++m)
      #pragma unroll
      for (int n = 0; n < 4; ++n)
        acc[m][n] = __builtin_amdgcn_mfma_f32_16x16x32_bf16(av[m], bv[n], acc[m][n], 0, 0, 0);
    __builtin_amdgcn_s_setprio(0);
  };

  stage(0);
  stage(1);
  wait_vm<3>();
  hard_barrier();

  #pragma unroll 3
  for (int t = 0; t < NT; ++t) {
    if (t + 2 < NT) stage(t + 2);
    compute(t);
    if (t + 2 < NT) {
      wait_vm<3>();
      hard_barrier();
    } else if (t + 1 < NT) {
      wait_vm<0>();
      hard_barrier();
    }
  }
}

// ---------- kernel 1: qkv GEMM; epilogue emits q (elu+1), kT (elu+1), vT ----
__global__ __launch_bounds__(512, 4) void gemm_qkv_kernel(const ushort* __restrict__ xb,
                                                          const ushort* __restrict__ wt,
                                                          ushort* __restrict__ q,
                                                          ushort* __restrict__ kT,
                                                          ushort* __restrict__ vT) {
  __shared__ ushort lds[36864];  // 72 KiB -> 2 blocks/CU
  f32x4 acc[4][4] = {};
  const int row0 = blockIdx.x * 128;
  const int col0 = blockIdx.y * 256;
  gemm_core32<1024, 1024, 32>(xb, wt, row0, col0, acc, lds);
  const int l = threadIdx.x & 63;
  const int wid = threadIdx.x >> 6;
  const int wr = wid >> 2, wc = wid & 3;
  const int fr = l & 15, fq = l >> 4;
  #pragma unroll
  for (int m = 0; m < 4; ++m) {
    #pragma unroll
    for (int n = 0; n < 4; ++n) {
      const int c = col0 + wc * 64 + n * 16 + fr;
      const int r0 = row0 + wr * 64 + m * 16 + fq * 4;  // j=0..3 consecutive rows
      if (c < 512) {
        #pragma unroll
        for (int j = 0; j < 4; ++j)
          q[(size_t)(r0 + j) * 512 + c] = f2bf(elu1(acc[m][n][j]));
      } else if (c < 1024) {
        const int d = c - 512;
        const int bh = (r0 >> 12) * 8 + (d >> 6);
        const int nn = r0 & 4095;
        ushort4 o;
        o.x = f2bf(elu1(acc[m][n][0]));
        o.y = f2bf(elu1(acc[m][n][1]));
        o.z = f2bf(elu1(acc[m][n][2]));
        o.w = f2bf(elu1(acc[m][n][3]));
        *(ushort4*)&kT[((size_t)bh * 64 + (d & 63)) * 4096 + nn] = o;
      } else {
        const int d = c - 1024;
        const int bh = (r0 >> 12) * 8 + (d >> 6);
        const int nn = r0 & 4095;
        ushort4 o;
        o.x = f2bf(acc[m][n][0]);
        o.y = f2bf(acc[m][n][1]);
        o.z = f2bf(acc[m][n][2]);
        o.w = f2bf(acc[m][n][3]);
        *(ushort4*)&vT[((size_t)bh * 64 + (d & 63)) * 4096 + nn] = o;
      }
    }
  }
}

// ---------- kernel 2: ctx partials via MFMA; 16 splits (2 blocks/CU) ----------
// part[sp][bh][d][e] = sum_{n in split sp} kT[bh][d][n] * vT[bh][e][n]
// grid (32 bh, 16 sp) = 512 blocks; 256 thr = 4 waves (2x2 of 32x32);
// NT=8 tiles of BK=32 (256 tokens/split). 4 rotating slots, waits 4/2/0.
__global__ __launch_bounds__(256) void ctx_mfma_kernel(const ushort* __restrict__ kT,
                                                       const ushort* __restrict__ vT,
                                                       float* __restrict__ part) {
  __shared__ ushort lds[16384];  // 32 KiB
  const int bh = blockIdx.x;
  const int sp = blockIdx.y;  // 0..15
  const int tid = threadIdx.x;
  const int l = tid & 63, wid = tid >> 6;
  const int fr = l & 15, fq = l >> 4;
  const int wr = wid >> 1, wc = wid & 1;

  const size_t base = (size_t)bh * 64 * 4096 + sp * 256;
  const int srow = tid >> 2;                     // 0..63
  const int lam = (tid & 3) ^ ((tid >> 3) & 3);  // logical 16B slot for phys (tid&3)
  const ushort* aG = kT + base + (size_t)srow * 4096 + lam * 8;
  const ushort* bG = vT + base + (size_t)srow * 4096 + lam * 8;

  auto stage = [&](int t) {
    ushort* d = lds + (t & 3) * 4096 + tid * 8;
    gload_lds16(aG + t * 32, d);
    gload_lds16(bG + t * 32, d + 2048);
  };

  const int sig = fq ^ ((fr >> 1) & 3);
  f32x4 acc[2][2] = {};

  auto compute = [&](int t) {
    const ushort* sb = lds + (t & 3) * 4096;
    bf16x8 av[2], bv[2];
    #pragma unroll
    for (int mm = 0; mm < 2; ++mm)
      av[mm] = *(const bf16x8*)&sb[(wr * 32 + mm * 16 + fr) * 32 + sig * 8];
    #pragma unroll
    for (int nn = 0; nn < 2; ++nn)
      bv[nn] = *(const bf16x8*)&sb[2048 + (wc * 32 + nn * 16 + fr) * 32 + sig * 8];
    #pragma unroll
    for (int mm = 0; mm < 2; ++mm)
      #pragma unroll
      for (int nn = 0; nn < 2; ++nn)
        acc[mm][nn] = __builtin_amdgcn_mfma_f32_16x16x32_bf16(av[mm], bv[nn], acc[mm][nn], 0, 0, 0);
  };

  constexpr int NT = 8;
  stage(0); stage(1); stage(2);
  for (int t = 0; t < NT; ++t) {
    if (t <= NT - 3) wait_vm<4>();
    else if (t == NT - 2) wait_vm<2>();
    else wait_vm<0>();
    hard_barrier();
    compute(t);
    hard_barrier();
    if (t + 3 < NT) stage(t + 3);
  }

  float* dst = part + ((size_t)sp * 32 + bh) * 4096;
  #pragma unroll
  for (int mm = 0; mm < 2; ++mm)
    #pragma unroll
    for (int nn = 0; nn < 2; ++nn)
      #pragma unroll
      for (int j = 0; j < 4; ++j)
        dst[(wr * 32 + mm * 16 + fq * 4 + j) * 64 + wc * 32 + nn * 16 + fr] = acc[mm][nn][j];
}

// ---------- kernel 3: W_eff^T (folds the 16-way split reduction) ----------
__global__ __launch_bounds__(256) void weff_kernel(const float* __restrict__ part,
                                                   const float* __restrict__ Wout,
                                                   ushort* __restrict__ weff) {
  const int bh = blockIdx.x;  // b*8+h
  const int h = bh & 7;
  const int m0 = blockIdx.y * 128;
  const int t = threadIdx.x;
  __shared__ float cs[64 * 64];
  __shared__ float ws[64][128];
  #pragma unroll
  for (int p = 0; p < 4; ++p) {
    const int idx = p * 1024 + t * 4;
    f32x4 s = {};
    #pragma unroll
    for (int sp = 0; sp < 16; ++sp)
      s += *(const f32x4*)&part[(size_t)sp * 131072 + (size_t)bh * 4096 + idx];
    *(f32x4*)&cs[idx] = s;
  }
  #pragma unroll
  for (int p = 0; p < 8; ++p) {
    const int e = (t >> 5) + p * 8;
    const int c = (t & 31) * 4;
    *(float4*)&ws[e][c] = *(const float4*)&Wout[(size_t)(h * 64 + e) * 1024 + m0 + c];
  }
  __syncthreads();
  const int m = t & 127;
  const int dh = (t >> 7) * 32;
  float acc[32] = {};
  for (int e = 0; e < 64; ++e) {
    const float w = ws[e][m];
    #pragma unroll
    for (int i = 0; i < 32; ++i)
      acc[i] += cs[(dh + i) * 64 + e] * w;
  }
  ushort* dst = weff + ((size_t)(bh >> 3) * 1024 + m0 + m) * 512 + h * 64 + dh;
  #pragma unroll
  for (int i = 0; i < 32; ++i) dst[i] = f2bf(acc[i]);
}

// ---------- kernel 4: out = q @ W_eff^T + b_out (fp32 out) ----------
__global__ __launch_bounds__(512, 4) void gemm_out_kernel(const ushort* __restrict__ q,
                                                          const ushort* __restrict__ weff,
                                                          const float* __restrict__ bout,
                                                          float* __restrict__ out) {
  __shared__ ushort lds[36864];  // 72 KiB -> 2 blocks/CU, grid 512 = 1 round
  f32x4 acc[4][4] = {};
  const int row0 = blockIdx.x * 128;
  const int col0 = blockIdx.y * 256;
  const int b = row0 >> 12;  // row0 / 4096
  gemm_core32<512, 512, 16>(q, weff + (size_t)b * 1024 * 512, row0, col0, acc, lds);
  const int l = threadIdx.x & 63;
  const int wid = threadIdx.x >> 6;
  const int wr = wid >> 2, wc = wid & 3;
  const int fr = l & 15, fq = l >> 4;
  #pragma unroll
  for (int m = 0; m < 4; ++m) {
    #pragma unroll
    for (int n = 0; n < 4; ++n) {
      const int c = col0 + wc * 64 + n * 16 + fr;
      const float bb = bout[c];
      #pragma unroll
      for (int j = 0; j < 4; ++j) {
        const int r = row0 + wr * 64 + m * 16 + fq * 4 + j;
        out[(size_t)r * 1024 + c] = acc[m][n][j] + bb;
      }
    }
  }
}

extern "C" void kernel_launch(void* const* d_in, const int* in_sizes, int n_in,
                              void* d_out, int out_size, void* d_ws, size_t ws_size,
                              hipStream_t stream) {
  const float* x    = (const float*)d_in[0];
  const float* Wqkv = (const float*)d_in[1];
  const float* Wout = (const float*)d_in[2];
  const float* bout = (const float*)d_in[3];
  float* out = (float*)d_out;
  char* ws = (char*)d_ws;

  // workspace layout (bytes). part aliases xb (xb dead after gemm_qkv).
  ushort* xb   = (ushort*)(ws);              // 16384*1024*2  = 33554432
  float*  part = (float* )(ws);              // 16*32*4096*4  = 8388608 (alias)
  ushort* wt   = (ushort*)(ws + 33554432);   // 1536*1024*2   = 3145728
  ushort* q    = (ushort*)(ws + 36700160);   // 16384*512*2   = 16777216
  ushort* kT   = (ushort*)(ws + 53477376);   // 32*64*4096*2  = 16777216
  ushort* vT   = (ushort*)(ws + 70254592);   // 32*64*4096*2  = 16777216
  ushort* weff = (ushort*)(ws + 87556096);   // 4*1024*512*2  = 4194304

  prep_kernel<<<3584, 256, 0, stream>>>((const float4*)x, (ushort4*)xb, Wqkv, wt);
  gemm_qkv_kernel<<<dim3(128, 6), 512, 0, stream>>>(xb, wt, q, kT, vT);
  ctx_mfma_kernel<<<dim3(32, 16), 256, 0, stream>>>(kT, vT, part);
  weff_kernel<<<dim3(32, 8), 256, 0, stream>>>(part, Wout, weff);
  gemm_out_kernel<<<dim3(128, 4), 512, 0, stream>>>(q, weff, bout, out);
}